// Round 8
// baseline (250.351 us; speedup 1.0000x reference)
//
#include <hip/hip_runtime.h>

#define SCALE 0.125f

constexpr int L_ = 1024, T_ = 1024, D_ = 64, HB_ = 64, QB = 16;

using f32x4 = __attribute__((ext_vector_type(4))) float;
using half8 = __attribute__((ext_vector_type(8))) _Float16;
using half4 = __attribute__((ext_vector_type(4))) _Float16;

// One block = 16 q-rows x full T for one (h,b). 4 waves; wave w owns
// t-subtile w*16..+15 of each 64-t chunk for BOTH QK^T and PV (PV consumes
// E straight from registers via zero-padded K=32 MFMA slots -> no E barrier).
// 2 barriers/chunk; depth-2 prefetch of K/V/prev (2 register sets).
// Epilogue: cross-wave O reduce via LDS union with Ks/Vt, then barrier-free
// normalized att streaming from El.
__global__ __launch_bounds__(256, 3) void attn_fused(
    const float* __restrict__ q, const float* __restrict__ kk,
    const float* __restrict__ vv, const float* __restrict__ prev,
    float* __restrict__ out, float* __restrict__ att) {
  __shared__ __align__(16) _Float16 El[QB][1032];   // 33024 B unnormalized E
  __shared__ __align__(16) unsigned char KV[18432]; // Ks|Vt, later ob4
  __shared__ float zb[4][16];

  auto Ks  = (_Float16(*)[72])KV;           // [64][72] K chunk rows (f16)
  auto Vt  = (_Float16(*)[72])(KV + 9216);  // [64][72] V^T chunk [d][t]
  auto ob4 = (float(*)[16][72])KV;          // [4][16][72] O partials (union)

  const int ltile = blockIdx.x;   // 0..63
  const int hb    = blockIdx.y;   // 0..63
  const int tid = threadIdx.x;
  const int w = tid >> 6, l = tid & 63, l15 = l & 15, lg = l >> 4;
  const int qrow = ltile * QB + l15;

  // Q B-frag (swapped QK^T): lane holds Q[qrow][f*32 + lg*8 + e]
  half8 qb2[2];
  {
    const float* qp = q + ((size_t)hb * L_ + qrow) * D_ + lg * 8;
#pragma unroll
    for (int f = 0; f < 2; ++f)
#pragma unroll
      for (int e = 0; e < 8; ++e) qb2[f][e] = (_Float16)qp[f * 32 + e];
  }

  const float* prow =
      prev + ((size_t)hb * L_ + qrow) * (size_t)T_ + w * 16 + lg * 4;
  const float* kbase = kk + (size_t)hb * T_ * D_;
  const float* vbase = vv + (size_t)hb * T_ * D_;

  // cooperative staging (64 t-rows x 64 d per chunk), depth-2 (2 reg sets)
  const int sr = tid >> 2;        // t-row 0..63
  const int sc = (tid & 3) * 16;  // K d-col base
  const int dj = (tid & 3) * 4;   // V d interleave base

  float4 kq[2][4], vq[2][4];
  f32x4 pbv[2];
  auto kload = [&](int c, int s) {
    const float* p = kbase + (size_t)(c * 64 + sr) * D_ + sc;
#pragma unroll
    for (int i = 0; i < 4; ++i) kq[s][i] = *(const float4*)(p + i * 4);
  };
  auto vload = [&](int c, int s) {
    const float* p = vbase + (size_t)(c * 64 + sr) * D_;
#pragma unroll
    for (int i = 0; i < 4; ++i) vq[s][i] = *(const float4*)(p + i * 16 + dj);
  };
  auto pload = [&](int c, int s) { pbv[s] = *(const f32x4*)(prow + c * 64); };
  auto kwrite = [&](int s) {
    half8 h0, h1;
    const float* f0 = (const float*)&kq[s][0];
    const float* f1 = (const float*)&kq[s][2];
#pragma unroll
    for (int e = 0; e < 8; ++e) {
      h0[e] = (_Float16)f0[e];
      h1[e] = (_Float16)f1[e];
    }
    *(half8*)&Ks[sr][sc] = h0;
    *(half8*)&Ks[sr][sc + 8] = h1;
  };
  auto vwrite = [&](int s) {  // transpose scatter (r5/r7-proven)
#pragma unroll
    for (int i = 0; i < 4; ++i) {
      Vt[i * 16 + dj + 0][sr] = (_Float16)vq[s][i].x;
      Vt[i * 16 + dj + 1][sr] = (_Float16)vq[s][i].y;
      Vt[i * 16 + dj + 2][sr] = (_Float16)vq[s][i].z;
      Vt[i * 16 + dj + 3][sr] = (_Float16)vq[s][i].w;
    }
  };

  // prologue: stage chunk 0; chunk 1 in flight in set 1
  kload(0, 0); vload(0, 0); pload(0, 0);
  kwrite(0); vwrite(0);
  kload(1, 1); vload(1, 1); pload(1, 1);

  float zsum = 0.f;
  f32x4 oacc[4];
#pragma unroll
  for (int nd = 0; nd < 4; ++nd) oacc[nd] = (f32x4){0.f, 0.f, 0.f, 0.f};

#pragma unroll 2
  for (int c = 0; c < 16; ++c) {
    __syncthreads();                 // K/V tile c staged for all waves
    f32x4 pv = pbv[c & 1];           // read before reissuing this set
    if (c < 14) {                    // issue chunk c+2 into freed set
      kload(c + 2, c & 1);
      vload(c + 2, c & 1);
      pload(c + 2, c & 1);
    }

    // QK^T (swapped): acc[i] = S^T[t = c*64 + w*16 + lg*4 + i][q = qrow]
    const int trow = w * 16 + l15;
    half8 ka0 = *(const half8*)&Ks[trow][lg * 8];
    half8 ka1 = *(const half8*)&Ks[trow][32 + lg * 8];
    f32x4 acc = {0.f, 0.f, 0.f, 0.f};
    acc = __builtin_amdgcn_mfma_f32_16x16x32_f16(ka0, qb2[0], acc, 0, 0, 0);
    acc = __builtin_amdgcn_mfma_f32_16x16x32_f16(ka1, qb2[1], acc, 0, 0, 0);

    float e0 = __expf(acc[0] * SCALE + pv[0]);
    float e1 = __expf(acc[1] * SCALE + pv[1]);
    float e2 = __expf(acc[2] * SCALE + pv[2]);
    float e3 = __expf(acc[3] * SCALE + pv[3]);
    zsum += (e0 + e1) + (e2 + e3);
    half4 ev;
    ev[0] = (_Float16)e0; ev[1] = (_Float16)e1;
    ev[2] = (_Float16)e2; ev[3] = (_Float16)e3;
    *(half4*)&El[l15][c * 64 + w * 16 + lg * 4] = ev;   // for phase B only

    // PV from registers: A k-slot lg*8+i := E[q=l15][t=...lg*4+i], upper 4 = 0
    half8 af;
    af[0] = ev[0]; af[1] = ev[1]; af[2] = ev[2]; af[3] = ev[3];
    af[4] = af[5] = af[6] = af[7] = (_Float16)0.f;
#pragma unroll
    for (int nd = 0; nd < 4; ++nd) {
      half4 v4 = *(const half4*)&Vt[nd * 16 + l15][w * 16 + lg * 4];
      half8 vb;
      vb[0] = v4[0]; vb[1] = v4[1]; vb[2] = v4[2]; vb[3] = v4[3];
      vb[4] = vb[5] = vb[6] = vb[7] = (_Float16)0.f;
      oacc[nd] = __builtin_amdgcn_mfma_f32_16x16x32_f16(af, vb, oacc[nd], 0, 0, 0);
    }

    __syncthreads();                 // all waves done reading Ks/Vt tile c
    if (c < 15) { kwrite((c + 1) & 1); vwrite((c + 1) & 1); }
  }

  // Z partials: zsum covers (q=l15, wave's t-slices); reduce lg groups
  zsum += __shfl_xor(zsum, 16, 64);
  zsum += __shfl_xor(zsum, 32, 64);
  if (lg == 0) zb[w][l15] = zsum;

  // O partials -> LDS (Ks/Vt region; safe after final barrier above)
#pragma unroll
  for (int nd = 0; nd < 4; ++nd)
#pragma unroll
    for (int i = 0; i < 4; ++i)
      ob4[w][lg * 4 + i][nd * 16 + l15] = oacc[nd][i];
  __syncthreads();

  // final O: thread -> q = tid>>4, d run (tid&15)*4
  {
    const int qq = tid >> 4, dd = (tid & 15) * 4;
    const float z =
        (zb[0][qq] + zb[1][qq]) + (zb[2][qq] + zb[3][qq]);
    const float rzq = 1.0f / z;
    f32x4 o0 = *(const f32x4*)&ob4[0][qq][dd];
    f32x4 o1 = *(const f32x4*)&ob4[1][qq][dd];
    f32x4 o2 = *(const f32x4*)&ob4[2][qq][dd];
    f32x4 o3 = *(const f32x4*)&ob4[3][qq][dd];
    f32x4 o = ((o0 + o1) + (o2 + o3));
    o[0] *= rzq; o[1] *= rzq; o[2] *= rzq; o[3] *= rzq;
    *(f32x4*)(out + ((size_t)hb * L_ + ltile * QB + qq) * (size_t)D_ + dd) = o;
  }

  // phase B: barrier-free normalized att streaming from El
  {
    const int row = tid >> 4, tc = tid & 15;
    const float z =
        (zb[0][row] + zb[1][row]) + (zb[2][row] + zb[3][row]);
    const float rzr = 1.0f / z;
    float* attw =
        att + ((size_t)hb * L_ + ltile * QB + row) * (size_t)T_ + tc * 4;
    const _Float16* ep = &El[row][tc * 4];
#pragma unroll
    for (int j = 0; j < 16; ++j) {
      half4 ev = *(const half4*)(ep + j * 64);
      f32x4 s = {(float)ev[0] * rzr, (float)ev[1] * rzr,
                 (float)ev[2] * rzr, (float)ev[3] * rzr};
      *(f32x4*)(attw + j * 64) = s;
    }
  }
}

extern "C" void kernel_launch(void* const* d_in, const int* in_sizes, int n_in,
                              void* d_out, int out_size, void* d_ws,
                              size_t ws_size, hipStream_t stream) {
  const float* q    = (const float*)d_in[0];  // (H,B,L,D)
  const float* k    = (const float*)d_in[1];  // (H,B,T,D)
  const float* v    = (const float*)d_in[2];  // (H,B,T,D)
  const float* prev = (const float*)d_in[3];  // (H,B,L,T)

  float* out = (float*)d_out;                 // (H,B,L,D)
  float* att = out + (size_t)HB_ * L_ * D_;   // (H,B,L,T)

  dim3 grid(L_ / QB, HB_);
  attn_fused<<<grid, 256, 0, stream>>>(q, k, v, prev, out, att);
}

// Round 9
// 248.467 us; speedup vs baseline: 1.0076x; 1.0076x over previous
//
#include <hip/hip_runtime.h>

#define SCALE 0.125f

constexpr int L_ = 1024, T_ = 1024, D_ = 64, HB_ = 64, QB = 16;

using f32x4  = __attribute__((ext_vector_type(4))) float;
using half8  = __attribute__((ext_vector_type(8))) _Float16;
using half4  = __attribute__((ext_vector_type(4))) _Float16;
using half2v = __attribute__((ext_vector_type(2))) _Float16;

// Raw barrier: LDS-visibility only (lgkmcnt), NO vmem drain. The compiler's
// automatic register-dependence vmcnt waits keep the reg-staged loads correct;
// prefetched global loads stay in flight across the barrier (T4).
#define BARRIER() asm volatile("s_waitcnt lgkmcnt(0)\n\ts_barrier" ::: "memory")

// One block = 16 q-rows x full T for one (h,b). 4 waves; wave w owns
// t-subtile w*16..+15 of each 64-t chunk for QK^T and PV (PV from registers
// via zero-padded K=32 MFMA slots). 2 raw barriers/chunk; depth-2 prefetch.
__global__ __launch_bounds__(256, 3) void attn_fused(
    const float* __restrict__ q, const float* __restrict__ kk,
    const float* __restrict__ vv, const float* __restrict__ prev,
    float* __restrict__ out, float* __restrict__ att) {
  __shared__ __align__(16) _Float16 El[QB][1032];   // 33024 B unnormalized E
  __shared__ __align__(16) unsigned char KV[18432]; // Ks|Vt, later ob4
  __shared__ float zb[4][16];

  auto Ks  = (_Float16(*)[72])KV;           // [64][72] K chunk rows (f16)
  auto Vt  = (_Float16(*)[72])(KV + 9216);  // [64][72] V^T chunk [d][t]
  auto ob4 = (float(*)[16][72])KV;          // [4][16][72] O partials (union)

  const int ltile = blockIdx.x;   // 0..63
  const int hb    = blockIdx.y;   // 0..63
  const int tid = threadIdx.x;
  const int w = tid >> 6, l = tid & 63, l15 = l & 15, lg = l >> 4;
  const int qrow = ltile * QB + l15;

  // Q B-frag (swapped QK^T): lane holds Q[qrow][f*32 + lg*8 + e]
  half8 qb2[2];
  {
    const float* qp = q + ((size_t)hb * L_ + qrow) * D_ + lg * 8;
#pragma unroll
    for (int f = 0; f < 2; ++f)
#pragma unroll
      for (int e = 0; e < 8; ++e) qb2[f][e] = (_Float16)qp[f * 32 + e];
  }

  const float* prow =
      prev + ((size_t)hb * L_ + qrow) * (size_t)T_ + w * 16 + lg * 4;
  const float* kbase = kk + (size_t)hb * T_ * D_;
  const float* vbase = vv + (size_t)hb * T_ * D_;

  // K staging: thread -> t-row sr, 16 d (two b128 LDS writes)
  const int sr = tid >> 2;        // 0..63
  const int sc = (tid & 3) * 16;  // 0,16,32,48
  // V staging: thread -> 4x4 block (t = sv_t..+3, d = sv_d..+3);
  // transposed write as 8x ds_write_b32, ~2-way banking.
  const int sv_d = (tid & 15) * 4;
  const int sv_t = (tid >> 4) * 4;

  f32x4 kq[2][4], vq[2][4];
  f32x4 pbv[2];
  auto kload = [&](int c, int s) {
    const float* p = kbase + (size_t)(c * 64 + sr) * D_ + sc;
#pragma unroll
    for (int i = 0; i < 4; ++i) kq[s][i] = *(const f32x4*)(p + i * 4);
  };
  auto vload = [&](int c, int s) {
    const float* p = vbase + (size_t)(c * 64 + sv_t) * D_ + sv_d;
#pragma unroll
    for (int j = 0; j < 4; ++j) vq[s][j] = *(const f32x4*)(p + j * D_);
  };
  auto pload = [&](int c, int s) { pbv[s] = *(const f32x4*)(prow + c * 64); };
  auto kwrite = [&](int s) {
    half8 h0, h1;
#pragma unroll
    for (int e = 0; e < 4; ++e) {
      h0[e]     = (_Float16)kq[s][0][e];
      h0[4 + e] = (_Float16)kq[s][1][e];
      h1[e]     = (_Float16)kq[s][2][e];
      h1[4 + e] = (_Float16)kq[s][3][e];
    }
    *(half8*)&Ks[sr][sc] = h0;
    *(half8*)&Ks[sr][sc + 8] = h1;
  };
  auto vwrite = [&](int s) {
#pragma unroll
    for (int dd = 0; dd < 4; ++dd) {
      half2v a, b;
      a[0] = (_Float16)vq[s][0][dd]; a[1] = (_Float16)vq[s][1][dd];
      b[0] = (_Float16)vq[s][2][dd]; b[1] = (_Float16)vq[s][3][dd];
      *(half2v*)&Vt[sv_d + dd][sv_t]     = a;
      *(half2v*)&Vt[sv_d + dd][sv_t + 2] = b;
    }
  };

  // prologue: stage chunk 0; chunk 1 in flight in set 1
  kload(0, 0); vload(0, 0); pload(0, 0);
  kwrite(0); vwrite(0);
  kload(1, 1); vload(1, 1); pload(1, 1);

  float zsum = 0.f;
  f32x4 oacc[4];
#pragma unroll
  for (int nd = 0; nd < 4; ++nd) oacc[nd] = (f32x4){0.f, 0.f, 0.f, 0.f};

#pragma unroll 2
  for (int c = 0; c < 16; ++c) {
    BARRIER();                       // K/V tile c staged (no vmem drain)
    f32x4 pv = pbv[c & 1];           // read before reissuing this set
    if (c < 14) {                    // issue chunk c+2 into freed set
      kload(c + 2, c & 1);
      vload(c + 2, c & 1);
      pload(c + 2, c & 1);
    }

    __builtin_amdgcn_s_setprio(1);
    // QK^T (swapped): acc[i] = S^T[t = c*64 + w*16 + lg*4 + i][q = qrow]
    const int trow = w * 16 + l15;
    half8 ka0 = *(const half8*)&Ks[trow][lg * 8];
    half8 ka1 = *(const half8*)&Ks[trow][32 + lg * 8];
    f32x4 acc = {0.f, 0.f, 0.f, 0.f};
    acc = __builtin_amdgcn_mfma_f32_16x16x32_f16(ka0, qb2[0], acc, 0, 0, 0);
    acc = __builtin_amdgcn_mfma_f32_16x16x32_f16(ka1, qb2[1], acc, 0, 0, 0);

    float e0 = __expf(acc[0] * SCALE + pv[0]);
    float e1 = __expf(acc[1] * SCALE + pv[1]);
    float e2 = __expf(acc[2] * SCALE + pv[2]);
    float e3 = __expf(acc[3] * SCALE + pv[3]);
    zsum += (e0 + e1) + (e2 + e3);
    half4 ev;
    ev[0] = (_Float16)e0; ev[1] = (_Float16)e1;
    ev[2] = (_Float16)e2; ev[3] = (_Float16)e3;
    *(half4*)&El[l15][c * 64 + w * 16 + lg * 4] = ev;   // for att phase only

    // PV from registers: A k-slot lg*8+i := E[q=l15][t=...lg*4+i], rest 0
    half8 af;
    af[0] = ev[0]; af[1] = ev[1]; af[2] = ev[2]; af[3] = ev[3];
    af[4] = af[5] = af[6] = af[7] = (_Float16)0.f;
#pragma unroll
    for (int nd = 0; nd < 4; ++nd) {
      half4 v4 = *(const half4*)&Vt[nd * 16 + l15][w * 16 + lg * 4];
      half8 vb;
      vb[0] = v4[0]; vb[1] = v4[1]; vb[2] = v4[2]; vb[3] = v4[3];
      vb[4] = vb[5] = vb[6] = vb[7] = (_Float16)0.f;
      oacc[nd] = __builtin_amdgcn_mfma_f32_16x16x32_f16(af, vb, oacc[nd], 0, 0, 0);
    }
    __builtin_amdgcn_s_setprio(0);

    BARRIER();                       // all waves done reading Ks/Vt tile c
    if (c < 15) { kwrite((c + 1) & 1); vwrite((c + 1) & 1); }
  }

  // Z partials: zsum covers (q=l15, wave's t-slices); reduce lg groups
  zsum += __shfl_xor(zsum, 16, 64);
  zsum += __shfl_xor(zsum, 32, 64);
  if (lg == 0) zb[w][l15] = zsum;

  // O partials -> LDS (Ks/Vt region; safe after final loop barrier)
#pragma unroll
  for (int nd = 0; nd < 4; ++nd)
#pragma unroll
    for (int i = 0; i < 4; ++i)
      ob4[w][lg * 4 + i][nd * 16 + l15] = oacc[nd][i];
  __syncthreads();

  // final O: thread -> q = tid>>4, d run (tid&15)*4
  {
    const int qq = tid >> 4, dd = (tid & 15) * 4;
    const float z = (zb[0][qq] + zb[1][qq]) + (zb[2][qq] + zb[3][qq]);
    const float rzq = 1.0f / z;
    f32x4 o0 = *(const f32x4*)&ob4[0][qq][dd];
    f32x4 o1 = *(const f32x4*)&ob4[1][qq][dd];
    f32x4 o2 = *(const f32x4*)&ob4[2][qq][dd];
    f32x4 o3 = *(const f32x4*)&ob4[3][qq][dd];
    f32x4 o = ((o0 + o1) + (o2 + o3));
    o[0] *= rzq; o[1] *= rzq; o[2] *= rzq; o[3] *= rzq;
    *(f32x4*)(out + ((size_t)hb * L_ + ltile * QB + qq) * (size_t)D_ + dd) = o;
  }

  // att phase: barrier-free normalized streaming from El
  {
    const int row = tid >> 4, tc = tid & 15;
    const float z = (zb[0][row] + zb[1][row]) + (zb[2][row] + zb[3][row]);
    const float rzr = 1.0f / z;
    float* attw =
        att + ((size_t)hb * L_ + ltile * QB + row) * (size_t)T_ + tc * 4;
    const _Float16* ep = &El[row][tc * 4];
#pragma unroll
    for (int j = 0; j < 16; ++j) {
      half4 ev = *(const half4*)(ep + j * 64);
      f32x4 s = {(float)ev[0] * rzr, (float)ev[1] * rzr,
                 (float)ev[2] * rzr, (float)ev[3] * rzr};
      *(f32x4*)(attw + j * 64) = s;
    }
  }
}

extern "C" void kernel_launch(void* const* d_in, const int* in_sizes, int n_in,
                              void* d_out, int out_size, void* d_ws,
                              size_t ws_size, hipStream_t stream) {
  const float* q    = (const float*)d_in[0];  // (H,B,L,D)
  const float* k    = (const float*)d_in[1];  // (H,B,T,D)
  const float* v    = (const float*)d_in[2];  // (H,B,T,D)
  const float* prev = (const float*)d_in[3];  // (H,B,L,T)

  float* out = (float*)d_out;                 // (H,B,L,D)
  float* att = out + (size_t)HB_ * L_ * D_;   // (H,B,L,T)

  dim3 grid(L_ / QB, HB_);
  attn_fused<<<grid, 256, 0, stream>>>(q, k, v, prev, out, att);
}